// Round 6
// baseline (199.853 us; speedup 1.0000x reference)
//
#include <hip/hip_runtime.h>
#include <cmath>

// Problem constants (B,C,H,W) = (16,3,512,512), window 11, patch 16.
#define OUTD 502          // 512 - 11 + 1
#define TSX  64           // output tile width
#define TSY  16           // output tile height
#define IH   26           // TSY + 10 staged input rows
#define NCOL 19           // 4-col groups per tile (76 cols >= 64+10)
#define SSTR 76           // stage row stride (bf16 elems, 152 B)
#define VSTRB 88          // v row stride in bf16 elems (176 B, 16B-aligned)
#define NTAP 11
#define GX   8            // ceil(502/64)
#define GY   32           // ceil(502/16)
#define NPARTIAL (48 * GY * GX)   // 12288

typedef float f32x4 __attribute__((ext_vector_type(4)));
typedef __bf16 bf16x4 __attribute__((ext_vector_type(4)));

struct GW { float g[NTAP]; };

__device__ __forceinline__ f32x4 splat4(float g) { return (f32x4){g, g, g, g}; }
__device__ __forceinline__ f32x4 vfma(float g, f32x4 a, f32x4 acc) {
    return __builtin_elementwise_fma(splat4(g), a, acc);
}

// Kernel 1: per-patch (16x16) max of the int mask -> small[b][32][32]
__global__ __launch_bounds__(256) void patch_max_kernel(const int* __restrict__ mask,
                                                        int* __restrict__ smallbuf) {
    const int py = blockIdx.x;   // 0..31 patch row
    const int b  = blockIdx.y;   // 0..15 image
    const int tid = threadIdx.x;
    const int lane = tid & 63, wv = tid >> 6;
    const int4* m4 = (const int4*)(mask + ((size_t)b << 18) + (size_t)py * 16 * 512);
    #pragma unroll
    for (int j = 0; j < 8; ++j) {
        int px  = wv + 4 * j;
        int row = lane >> 2, q = lane & 3;
        int4 v = m4[row * 128 + px * 4 + q];
        int mx = max(max(v.x, v.y), max(v.z, v.w));
        #pragma unroll
        for (int off = 32; off >= 1; off >>= 1) mx = max(mx, __shfl_xor(mx, off));
        if (lane == 0) smallbuf[((b << 5) + py) * 32 + px] = mx;
    }
}

// Kernel 2: fused separable-Gaussian SSIM over a 64x16 output tile.
// Inputs staged once in LDS as bf16 (RTNE); 4 stat maps (mu1, mu2, conv(ab),
// conv(a^2+b^2)) round-trip through LDS in bf16. Total LDS ~19.3 KB ->
// 8 blocks/CU (32 waves, all wave slots).
__global__ __launch_bounds__(256, 8) void ssim_kernel(const float* __restrict__ img1,
                                                      const float* __restrict__ img2,
                                                      const int* __restrict__ smallbuf,
                                                      float* __restrict__ partial, GW gw) {
    __shared__ __bf16 s1[IH * SSTR];         // 3952 B
    __shared__ __bf16 s2[IH * SSTR];         // 3952 B
    __shared__ __bf16 vb[4 * TSY * VSTRB];   // 11264 B
    __shared__ int sdil[10];                 // 2 patch-rows x 5 patch-cols
    __shared__ float wsum[4];

    const int tid = threadIdx.x;
    const int x0 = blockIdx.x * TSX, y0 = blockIdx.y * TSY;
    const int bc = blockIdx.z;               // b*3 + c
    const size_t base = (size_t)bc << 18;    // *512*512

    // Phase 0: stage both images (26 rows x 19 groups), clamped addresses,
    // f32 global load -> bf16 RTNE -> LDS. Clamped (OOB) rows/cols only ever
    // feed outputs the epilogue discards.
    for (int i = tid; i < IH * NCOL; i += 256) {   // 494 slots, 2 iters
        int r = i / NCOL, q = i - r * NCOL;
        int gy = y0 + r;     gy = gy > 511 ? 511 : gy;
        int gx = x0 + 4 * q; gx = gx > 508 ? 508 : gx;
        size_t off = base + ((size_t)gy << 9) + gx;
        f32x4 a = *(const f32x4*)(img1 + off);
        f32x4 b = *(const f32x4*)(img2 + off);
        *(bf16x4*)&s1[r * SSTR + 4 * q] = __builtin_convertvector(a, bf16x4);
        *(bf16x4*)&s2[r * SSTR + 4 * q] = __builtin_convertvector(b, bf16x4);
    }

    // fused 3x3 dilation lookup, done by wave 3 (light in phase 0)
    if (tid >= 192 && tid < 202) {
        int t = tid - 192;
        int pr = (int)blockIdx.y + (t >= 5 ? 1 : 0);       // y0>>4 == blockIdx.y
        int pc = (int)blockIdx.x * 4 + (t >= 5 ? t - 5 : t);
        int acc = 0;
        if (pr < 32 && pc < 32) {
            const int* sb = smallbuf + ((bc / 3) << 10);
            #pragma unroll
            for (int dy = -1; dy <= 1; ++dy)
                #pragma unroll
                for (int dx = -1; dx <= 1; ++dx) {
                    int ny = pr + dy, nx = pc + dx;
                    if (ny >= 0 && ny < 32 && nx >= 0 && nx < 32) acc |= sb[(ny << 5) + nx];
                }
        }
        sdil[t] = acc ? 1 : 0;
    }
    __syncthreads();

    // Phase 1: vertical Gaussian from LDS, 2 output rows per thread,
    // products computed once per input row; results stored bf16 (RTNE).
    if (tid < 8 * NCOL) {            // 152 tasks
        int rp = tid / NCOL, q = tid - rp * NCOL;
        int yb = 2 * rp;
        f32x4 z = splat4(0.f);
        f32x4 acc[2][4] = {{z, z, z, z}, {z, z, z, z}};
        #pragma unroll
        for (int r = 0; r < NTAP + 1; ++r) {
            bf16x4 ah = *(const bf16x4*)&s1[(yb + r) * SSTR + 4 * q];
            bf16x4 bh = *(const bf16x4*)&s2[(yb + r) * SSTR + 4 * q];
            f32x4 a = __builtin_convertvector(ah, f32x4);
            f32x4 b = __builtin_convertvector(bh, f32x4);
            f32x4 P = a * b;
            f32x4 S = __builtin_elementwise_fma(b, b, a * a);
            if (r < NTAP) {
                float g = gw.g[r];
                acc[0][0] = vfma(g, a, acc[0][0]);
                acc[0][1] = vfma(g, b, acc[0][1]);
                acc[0][2] = vfma(g, P, acc[0][2]);
                acc[0][3] = vfma(g, S, acc[0][3]);
            }
            if (r >= 1) {
                float g = gw.g[r - 1];
                acc[1][0] = vfma(g, a, acc[1][0]);
                acc[1][1] = vfma(g, b, acc[1][1]);
                acc[1][2] = vfma(g, P, acc[1][2]);
                acc[1][3] = vfma(g, S, acc[1][3]);
            }
        }
        #pragma unroll
        for (int o = 0; o < 2; ++o)
            #pragma unroll
            for (int m = 0; m < 4; ++m) {
                bf16x4 h = __builtin_convertvector(acc[o][m], bf16x4);
                *(bf16x4*)&vb[(m * TSY + yb + o) * VSTRB + 4 * q] = h;
            }
    }
    __syncthreads();

    // Phase 2: horizontal Gaussian, ALL 256 threads, 4 outputs per thread.
    const int row = tid >> 4, xq = tid & 15;   // 16 rows x 16 four-wide runs
    float oa[4][4];
    #pragma unroll
    for (int m = 0; m < 4; ++m) {
        const __bf16* vp = &vb[(m * TSY + row) * VSTRB + 4 * xq];
        float w[16];
        #pragma unroll
        for (int i = 0; i < 4; ++i) {
            bf16x4 t = *(const bf16x4*)&vp[4 * i];
            *(f32x4*)&w[4 * i] = __builtin_convertvector(t, f32x4);
        }
        #pragma unroll
        for (int j = 0; j < 4; ++j) {
            float s = 0.f;
            #pragma unroll
            for (int k = 0; k < NTAP; ++k) s = fmaf(gw.g[k], w[j + k], s);
            oa[m][j] = s;
        }
    }

    // Epilogue: SSIM + valid mask + local sum
    const float C1v = 1e-4f, C2v = 9e-4f;  // L = 1 (inputs uniform [0,1))
    float lsum = 0.f;
    {
        const int y = y0 + row;
        const int lr1 = (row + 10) >> 4;       // row>>4 == 0 always
        #pragma unroll
        for (int j = 0; j < 4; ++j) {
            int xl = xq * 4 + j;
            int x = x0 + xl;
            if (y < OUTD && x < OUTD) {
                int lc0 = xl >> 4, lc1 = (xl + 10) >> 4;
                int validm = sdil[lc0] & sdil[lc1] &
                             sdil[5 * lr1 + lc0] & sdil[5 * lr1 + lc1];
                float mu1 = oa[0][j], mu2 = oa[1][j];
                float mu1s = mu1 * mu1, mu2s = mu2 * mu2, mu12 = mu1 * mu2;
                float sg12 = oa[2][j] - mu12;
                float sigS = oa[3][j] - mu1s - mu2s;
                float num = (2.f * mu12 + C1v) * (2.f * sg12 + C2v);
                float den = (mu1s + mu2s + C1v) * (sigS + C2v);
                if (validm) lsum += __fdividef(num, den);
            }
        }
    }

    // block reduction -> one float partial per block (deterministic, no atomics)
    #pragma unroll
    for (int off = 32; off >= 1; off >>= 1) lsum += __shfl_xor(lsum, off);
    if ((tid & 63) == 0) wsum[tid >> 6] = lsum;
    __syncthreads();
    if (tid == 0)
        partial[((int)blockIdx.z * GY + (int)blockIdx.y) * GX + (int)blockIdx.x] =
            wsum[0] + wsum[1] + wsum[2] + wsum[3];
}

// Kernel 3: reduce partials, divide by element count
__global__ __launch_bounds__(256) void finalize_kernel(const float* __restrict__ partial,
                                                       float* __restrict__ out) {
    __shared__ double sd[256];
    double s = 0.0;
    const f32x4* p4 = (const f32x4*)partial;
    for (int i = threadIdx.x; i < NPARTIAL / 4; i += 256) {
        f32x4 vv = p4[i];
        s += (double)vv.x + (double)vv.y + (double)vv.z + (double)vv.w;
    }
    sd[threadIdx.x] = s;
    __syncthreads();
    for (int st = 128; st >= 1; st >>= 1) {
        if (threadIdx.x < st) sd[threadIdx.x] += sd[threadIdx.x + st];
        __syncthreads();
    }
    if (threadIdx.x == 0) out[0] = (float)(sd[0] / 12096192.0);  // 16*3*502*502
}

extern "C" void kernel_launch(void* const* d_in, const int* in_sizes, int n_in,
                              void* d_out, int out_size, void* d_ws, size_t ws_size,
                              hipStream_t stream) {
    const float* img1 = (const float*)d_in[0];
    const float* img2 = (const float*)d_in[1];
    const int*   mask = (const int*)d_in[2];
    float* out = (float*)d_out;

    char* ws = (char*)d_ws;
    float* partial  = (float*)ws;                        // 12288 floats
    int*   smallbuf = (int*)(ws + NPARTIAL * 4);         // 16*32*32 ints

    // Gaussian(sigma=1.5), normalized in double then cast to float (matches np)
    GW gw;
    double gd[NTAP], gsum = 0.0;
    for (int i = 0; i < NTAP; ++i) {
        double x = (double)(i - 5);
        gd[i] = exp(-(x * x) / 4.5);
        gsum += gd[i];
    }
    for (int i = 0; i < NTAP; ++i) gw.g[i] = (float)(gd[i] / gsum);

    patch_max_kernel<<<dim3(32, 16), 256, 0, stream>>>(mask, smallbuf);
    ssim_kernel<<<dim3(GX, GY, 48), 256, 0, stream>>>(img1, img2, smallbuf, partial, gw);
    finalize_kernel<<<1, 256, 0, stream>>>(partial, out);
}

// Round 7
// 190.335 us; speedup vs baseline: 1.0500x; 1.0500x over previous
//
#include <hip/hip_runtime.h>
#include <cmath>

// Problem constants (B,C,H,W) = (16,3,512,512), window 11, patch 16.
#define OUTD 502          // 512 - 11 + 1
#define TSX  64           // output tile width
#define TSY  16           // output tile height
#define IH   26           // TSY + 10 staged input rows
#define NCOL 19           // 4-col groups per tile (76 cols >= 64+10)
#define SSTR 76           // stage row stride (bf16 elems, 152 B)
#define VSTRB 88          // v row stride in bf16 elems (176 B, 16B-aligned)
#define NTAP 11
#define GX   8            // ceil(502/64)
#define GY   32           // ceil(502/16)
#define NPARTIAL (48 * GY * GX)   // 12288

typedef float f32x4 __attribute__((ext_vector_type(4)));
typedef __bf16 bf16x4 __attribute__((ext_vector_type(4)));

struct GW { float g[NTAP]; };

__device__ __forceinline__ f32x4 splat4(float g) { return (f32x4){g, g, g, g}; }
__device__ __forceinline__ f32x4 vfma(float g, f32x4 a, f32x4 acc) {
    return __builtin_elementwise_fma(splat4(g), a, acc);
}

// Kernel 1: per-patch (16x16) max of the int mask -> small[b][32][32]
__global__ __launch_bounds__(256) void patch_max_kernel(const int* __restrict__ mask,
                                                        int* __restrict__ smallbuf) {
    const int py = blockIdx.x;   // 0..31 patch row
    const int b  = blockIdx.y;   // 0..15 image
    const int tid = threadIdx.x;
    const int lane = tid & 63, wv = tid >> 6;
    const int4* m4 = (const int4*)(mask + ((size_t)b << 18) + (size_t)py * 16 * 512);
    #pragma unroll
    for (int j = 0; j < 8; ++j) {
        int px  = wv + 4 * j;
        int row = lane >> 2, q = lane & 3;
        int4 v = m4[row * 128 + px * 4 + q];
        int mx = max(max(v.x, v.y), max(v.z, v.w));
        #pragma unroll
        for (int off = 32; off >= 1; off >>= 1) mx = max(mx, __shfl_xor(mx, off));
        if (lane == 0) smallbuf[((b << 5) + py) * 32 + px] = mx;
    }
}

// Kernel 2: fused separable-Gaussian SSIM over a 64x16 output tile.
// Inputs staged once in LDS as bf16 (RTNE); 4 stat maps (mu1, mu2, conv(ab),
// conv(a^2+b^2)) round-trip through LDS in bf16. Total LDS ~19.3 KB ->
// 8 blocks/CU by LDS. NOTE: plain __launch_bounds__(256) — the (256,8)
// variant capped VGPRs at 64 and spilled ~20 B/thread to scratch
// (WRITE_SIZE 384 KB -> 61 MB, R6 regression). Natural allocation is
// ~40 VGPR <= 64, which already permits 8 waves/SIMD at runtime.
__global__ __launch_bounds__(256) void ssim_kernel(const float* __restrict__ img1,
                                                   const float* __restrict__ img2,
                                                   const int* __restrict__ smallbuf,
                                                   float* __restrict__ partial, GW gw) {
    __shared__ __bf16 s1[IH * SSTR];         // 3952 B
    __shared__ __bf16 s2[IH * SSTR];         // 3952 B
    __shared__ __bf16 vb[4 * TSY * VSTRB];   // 11264 B
    __shared__ int sdil[10];                 // 2 patch-rows x 5 patch-cols
    __shared__ float wsum[4];

    const int tid = threadIdx.x;
    const int x0 = blockIdx.x * TSX, y0 = blockIdx.y * TSY;
    const int bc = blockIdx.z;               // b*3 + c
    const size_t base = (size_t)bc << 18;    // *512*512

    // Phase 0: stage both images (26 rows x 19 groups), clamped addresses,
    // f32 global load -> bf16 RTNE -> LDS. Clamped (OOB) rows/cols only ever
    // feed outputs the epilogue discards.
    for (int i = tid; i < IH * NCOL; i += 256) {   // 494 slots, 2 iters
        int r = i / NCOL, q = i - r * NCOL;
        int gy = y0 + r;     gy = gy > 511 ? 511 : gy;
        int gx = x0 + 4 * q; gx = gx > 508 ? 508 : gx;
        size_t off = base + ((size_t)gy << 9) + gx;
        f32x4 a = *(const f32x4*)(img1 + off);
        f32x4 b = *(const f32x4*)(img2 + off);
        *(bf16x4*)&s1[r * SSTR + 4 * q] = __builtin_convertvector(a, bf16x4);
        *(bf16x4*)&s2[r * SSTR + 4 * q] = __builtin_convertvector(b, bf16x4);
    }

    // fused 3x3 dilation lookup, done by wave 3 (light in phase 0)
    if (tid >= 192 && tid < 202) {
        int t = tid - 192;
        int pr = (int)blockIdx.y + (t >= 5 ? 1 : 0);       // y0>>4 == blockIdx.y
        int pc = (int)blockIdx.x * 4 + (t >= 5 ? t - 5 : t);
        int acc = 0;
        if (pr < 32 && pc < 32) {
            const int* sb = smallbuf + ((bc / 3) << 10);
            #pragma unroll
            for (int dy = -1; dy <= 1; ++dy)
                #pragma unroll
                for (int dx = -1; dx <= 1; ++dx) {
                    int ny = pr + dy, nx = pc + dx;
                    if (ny >= 0 && ny < 32 && nx >= 0 && nx < 32) acc |= sb[(ny << 5) + nx];
                }
        }
        sdil[t] = acc ? 1 : 0;
    }
    __syncthreads();

    // Phase 1: vertical Gaussian from LDS, 2 output rows per thread,
    // products computed once per input row; results stored bf16 (RTNE).
    if (tid < 8 * NCOL) {            // 152 tasks
        int rp = tid / NCOL, q = tid - rp * NCOL;
        int yb = 2 * rp;
        f32x4 z = splat4(0.f);
        f32x4 acc[2][4] = {{z, z, z, z}, {z, z, z, z}};
        #pragma unroll
        for (int r = 0; r < NTAP + 1; ++r) {
            bf16x4 ah = *(const bf16x4*)&s1[(yb + r) * SSTR + 4 * q];
            bf16x4 bh = *(const bf16x4*)&s2[(yb + r) * SSTR + 4 * q];
            f32x4 a = __builtin_convertvector(ah, f32x4);
            f32x4 b = __builtin_convertvector(bh, f32x4);
            f32x4 P = a * b;
            f32x4 S = __builtin_elementwise_fma(b, b, a * a);
            if (r < NTAP) {
                float g = gw.g[r];
                acc[0][0] = vfma(g, a, acc[0][0]);
                acc[0][1] = vfma(g, b, acc[0][1]);
                acc[0][2] = vfma(g, P, acc[0][2]);
                acc[0][3] = vfma(g, S, acc[0][3]);
            }
            if (r >= 1) {
                float g = gw.g[r - 1];
                acc[1][0] = vfma(g, a, acc[1][0]);
                acc[1][1] = vfma(g, b, acc[1][1]);
                acc[1][2] = vfma(g, P, acc[1][2]);
                acc[1][3] = vfma(g, S, acc[1][3]);
            }
        }
        #pragma unroll
        for (int o = 0; o < 2; ++o)
            #pragma unroll
            for (int m = 0; m < 4; ++m) {
                bf16x4 h = __builtin_convertvector(acc[o][m], bf16x4);
                *(bf16x4*)&vb[(m * TSY + yb + o) * VSTRB + 4 * q] = h;
            }
    }
    __syncthreads();

    // Phase 2: horizontal Gaussian, ALL 256 threads, 4 outputs per thread.
    const int row = tid >> 4, xq = tid & 15;   // 16 rows x 16 four-wide runs
    float oa[4][4];
    #pragma unroll
    for (int m = 0; m < 4; ++m) {
        const __bf16* vp = &vb[(m * TSY + row) * VSTRB + 4 * xq];
        float w[16];
        #pragma unroll
        for (int i = 0; i < 4; ++i) {
            bf16x4 t = *(const bf16x4*)&vp[4 * i];
            *(f32x4*)&w[4 * i] = __builtin_convertvector(t, f32x4);
        }
        #pragma unroll
        for (int j = 0; j < 4; ++j) {
            float s = 0.f;
            #pragma unroll
            for (int k = 0; k < NTAP; ++k) s = fmaf(gw.g[k], w[j + k], s);
            oa[m][j] = s;
        }
    }

    // Epilogue: SSIM + valid mask + local sum
    const float C1v = 1e-4f, C2v = 9e-4f;  // L = 1 (inputs uniform [0,1))
    float lsum = 0.f;
    {
        const int y = y0 + row;
        const int lr1 = (row + 10) >> 4;       // row>>4 == 0 always
        #pragma unroll
        for (int j = 0; j < 4; ++j) {
            int xl = xq * 4 + j;
            int x = x0 + xl;
            if (y < OUTD && x < OUTD) {
                int lc0 = xl >> 4, lc1 = (xl + 10) >> 4;
                int validm = sdil[lc0] & sdil[lc1] &
                             sdil[5 * lr1 + lc0] & sdil[5 * lr1 + lc1];
                float mu1 = oa[0][j], mu2 = oa[1][j];
                float mu1s = mu1 * mu1, mu2s = mu2 * mu2, mu12 = mu1 * mu2;
                float sg12 = oa[2][j] - mu12;
                float sigS = oa[3][j] - mu1s - mu2s;
                float num = (2.f * mu12 + C1v) * (2.f * sg12 + C2v);
                float den = (mu1s + mu2s + C1v) * (sigS + C2v);
                if (validm) lsum += __fdividef(num, den);
            }
        }
    }

    // block reduction -> one float partial per block (deterministic, no atomics)
    #pragma unroll
    for (int off = 32; off >= 1; off >>= 1) lsum += __shfl_xor(lsum, off);
    if ((tid & 63) == 0) wsum[tid >> 6] = lsum;
    __syncthreads();
    if (tid == 0)
        partial[((int)blockIdx.z * GY + (int)blockIdx.y) * GX + (int)blockIdx.x] =
            wsum[0] + wsum[1] + wsum[2] + wsum[3];
}

// Kernel 3: reduce partials, divide by element count
__global__ __launch_bounds__(256) void finalize_kernel(const float* __restrict__ partial,
                                                       float* __restrict__ out) {
    __shared__ double sd[256];
    double s = 0.0;
    const f32x4* p4 = (const f32x4*)partial;
    for (int i = threadIdx.x; i < NPARTIAL / 4; i += 256) {
        f32x4 vv = p4[i];
        s += (double)vv.x + (double)vv.y + (double)vv.z + (double)vv.w;
    }
    sd[threadIdx.x] = s;
    __syncthreads();
    for (int st = 128; st >= 1; st >>= 1) {
        if (threadIdx.x < st) sd[threadIdx.x] += sd[threadIdx.x + st];
        __syncthreads();
    }
    if (threadIdx.x == 0) out[0] = (float)(sd[0] / 12096192.0);  // 16*3*502*502
}

extern "C" void kernel_launch(void* const* d_in, const int* in_sizes, int n_in,
                              void* d_out, int out_size, void* d_ws, size_t ws_size,
                              hipStream_t stream) {
    const float* img1 = (const float*)d_in[0];
    const float* img2 = (const float*)d_in[1];
    const int*   mask = (const int*)d_in[2];
    float* out = (float*)d_out;

    char* ws = (char*)d_ws;
    float* partial  = (float*)ws;                        // 12288 floats
    int*   smallbuf = (int*)(ws + NPARTIAL * 4);         // 16*32*32 ints

    // Gaussian(sigma=1.5), normalized in double then cast to float (matches np)
    GW gw;
    double gd[NTAP], gsum = 0.0;
    for (int i = 0; i < NTAP; ++i) {
        double x = (double)(i - 5);
        gd[i] = exp(-(x * x) / 4.5);
        gsum += gd[i];
    }
    for (int i = 0; i < NTAP; ++i) gw.g[i] = (float)(gd[i] / gsum);

    patch_max_kernel<<<dim3(32, 16), 256, 0, stream>>>(mask, smallbuf);
    ssim_kernel<<<dim3(GX, GY, 48), 256, 0, stream>>>(img1, img2, smallbuf, partial, gw);
    finalize_kernel<<<1, 256, 0, stream>>>(partial, out);
}

// Round 9
// 186.463 us; speedup vs baseline: 1.0718x; 1.0208x over previous
//
#include <hip/hip_runtime.h>
#include <cmath>
#include <cstdint>
#include <cstring>

// Problem constants (B,C,H,W) = (16,3,512,512), window 11, patch 16.
#define OUTD 502          // 512 - 11 + 1
#define TSX  64           // output tile width
#define TSY  16           // output tile height
#define SPITCH 88         // staged row pitch (f16): 176 B, 16B-mult
#define SROWS  32         // 26 data rows + 6 zero pad (B-frag k reaches 31)
#define HTP    40         // per-wave transpose buffer pitch (f16): 80 B, 16B-mult
#define NTAP 11
#define GX   8            // ceil(502/64)
#define GY   32           // ceil(502/16)
#define NPARTIAL (48 * GY * GX)   // 12288

typedef float    f32x4 __attribute__((ext_vector_type(4)));
typedef float    f32x8 __attribute__((ext_vector_type(8)));
typedef _Float16 f16x4 __attribute__((ext_vector_type(4)));
typedef _Float16 f16x8 __attribute__((ext_vector_type(8)));

struct GW { float g[NTAP]; float cm; };  // g: fp16-rounded weights; cm = 1/(sum g)^2

__device__ __forceinline__ f32x4 mfma_f16(f16x8 a, f16x8 b, f32x4 c) {
    return __builtin_amdgcn_mfma_f32_16x16x32_f16(a, b, c, 0, 0, 0);
}

// Kernel 1: per-patch (16x16) max of the int mask -> small[b][32][32]
__global__ __launch_bounds__(256) void patch_max_kernel(const int* __restrict__ mask,
                                                        int* __restrict__ smallbuf) {
    const int py = blockIdx.x;   // 0..31 patch row
    const int b  = blockIdx.y;   // 0..15 image
    const int tid = threadIdx.x;
    const int lane = tid & 63, wv = tid >> 6;
    const int4* m4 = (const int4*)(mask + ((size_t)b << 18) + (size_t)py * 16 * 512);
    #pragma unroll
    for (int j = 0; j < 8; ++j) {
        int px  = wv + 4 * j;
        int row = lane >> 2, q = lane & 3;
        int4 v = m4[row * 128 + px * 4 + q];
        int mx = max(max(v.x, v.y), max(v.z, v.w));
        #pragma unroll
        for (int off = 32; off >= 1; off >>= 1) mx = max(mx, __shfl_xor(mx, off));
        if (lane == 0) smallbuf[((b << 5) + py) * 32 + px] = mx;
    }
}

// Kernel 2: MFMA-based separable-Gaussian SSIM over a 64x16 output tile.
// Both 11-tap convolutions are 16x16x32 *fp16* MFMAs with a Toeplitz A
// (A[m][k] = g[k-m]). fp16 (not bf16) for the whole data path: bf16's
// coarse ulp gave a ~0.02-ulp systematic bias in RTNE(a*b)/RTNE(a^2+b^2)
// that biased sg12 = Sab - mu1*mu2 and failed absmax by 1.1x (R8).
// fp16 ulp is 8x finer; same MFMA shape/throughput/layout.
__global__ __launch_bounds__(256) void ssim_kernel(const float* __restrict__ img1,
                                                   const float* __restrict__ img2,
                                                   const int* __restrict__ smallbuf,
                                                   float* __restrict__ partial, GW gw) {
    __shared__ _Float16 sA[2][SROWS][SPITCH];   // 11264 B: staged img1/img2 (f16)
    __shared__ _Float16 sHT[4][16][HTP];        //  5120 B: per-wave transpose buffers
    __shared__ int sdil[10];                    // 2 patch-rows x 5 patch-cols
    __shared__ float wsum[4];

    const int tid  = threadIdx.x;
    const int wv   = tid >> 6, lane = tid & 63;
    const int nidx = lane & 15, quad = lane >> 4;
    const int x0 = blockIdx.x * TSX, y0 = blockIdx.y * TSY;
    const int bc = blockIdx.z;               // b*3 + c
    const size_t base = (size_t)bc << 18;    // *512*512

    // Phase 0: stage both images, rows 0..25 from global (clamped addresses:
    // clamped data only ever reaches discarded outputs), rows 26..31 zeroed
    // (finite pad for B-frag over-reads; A is zero there anyway).
    for (int i = tid; i < SROWS * 20; i += 256) {   // 640 slots
        int r = i / 20, q = i - r * 20;
        if (r < 26) {
            int gy = y0 + r;     gy = gy > 511 ? 511 : gy;
            int gx = x0 + 4 * q; gx = gx > 508 ? 508 : gx;
            size_t off = base + ((size_t)gy << 9) + gx;
            f32x4 a = *(const f32x4*)(img1 + off);
            f32x4 b = *(const f32x4*)(img2 + off);
            *(f16x4*)&sA[0][r][4 * q] = __builtin_convertvector(a, f16x4);
            *(f16x4*)&sA[1][r][4 * q] = __builtin_convertvector(b, f16x4);
        } else {
            f16x4 z = {};
            *(f16x4*)&sA[0][r][4 * q] = z;
            *(f16x4*)&sA[1][r][4 * q] = z;
        }
    }

    // fused 3x3 dilation lookup for this tile's patch neighborhood
    if (tid >= 192 && tid < 202) {
        int t = tid - 192;
        int pr = (int)blockIdx.y + (t >= 5 ? 1 : 0);       // y0>>4 == blockIdx.y
        int pc = (int)blockIdx.x * 4 + (t >= 5 ? t - 5 : t);
        int acc = 0;
        if (pr < 32 && pc < 32) {
            const int* sb = smallbuf + ((bc / 3) << 10);
            #pragma unroll
            for (int dy = -1; dy <= 1; ++dy)
                #pragma unroll
                for (int dx = -1; dx <= 1; ++dx) {
                    int ny = pr + dy, nx = pc + dx;
                    if (ny >= 0 && ny < 32 && nx >= 0 && nx < 32) acc |= sb[(ny << 5) + nx];
                }
        }
        sdil[t] = acc ? 1 : 0;
    }
    __syncthreads();

    // Toeplitz A-frag (shared by both passes): A[m=nidx][k=quad*8+j] = g[k-m]
    f16x8 af;
    #pragma unroll
    for (int j = 0; j < 8; ++j) {
        int d = quad * 8 + j - nidx;
        float val = 0.f;
        #pragma unroll
        for (int t = 0; t < NTAP; ++t) val = (d == t) ? gw.g[t] : val;
        af[j] = (_Float16)val;
    }

    // This wave handles output cols cb..cb+15 of the tile.
    const int cb = 16 * wv;

    // Load raw a/b B-frags (2 row-halves each): lane = row 16h+nidx,
    // cols cb + quad*8 .. +7 (contiguous, 16B-aligned).
    f16x8 fr0[4], fr1[4];
    #pragma unroll
    for (int h = 0; h < 2; ++h) {
        f16x8 a = *(const f16x8*)&sA[0][16 * h + nidx][cb + quad * 8];
        f16x8 b = *(const f16x8*)&sA[1][16 * h + nidx][cb + quad * 8];
        if (h == 0) { fr0[0] = a; fr0[1] = b; } else { fr1[0] = a; fr1[1] = b; }
        f32x8 afl = __builtin_convertvector(a, f32x8);
        f32x8 bfl = __builtin_convertvector(b, f32x8);
        f32x8 P = afl * bfl;
        f32x8 S = afl * afl + bfl * bfl;
        if (h == 0) { fr0[2] = __builtin_convertvector(P, f16x8);
                      fr0[3] = __builtin_convertvector(S, f16x8); }
        else        { fr1[2] = __builtin_convertvector(P, f16x8);
                      fr1[3] = __builtin_convertvector(S, f16x8); }
    }

    // Per map: 2 horizontal MFMAs -> transpose through sHT[wv] -> 1 vertical MFMA.
    // All LDS deps are intra-wave (in-order DS pipe + compiler lgkmcnt waits).
    f32x4 accv[4];
    #pragma unroll
    for (int mm = 0; mm < 4; ++mm) {
        f32x4 z = {0.f, 0.f, 0.f, 0.f};
        f32x4 c0 = mfma_f16(af, fr0[mm], z);   // rows 0..15
        f32x4 c1 = mfma_f16(af, fr1[mm], z);   // rows 16..31
        // C layout: row(m=x') = quad*4+r, col(n=y) = nidx
        #pragma unroll
        for (int r = 0; r < 4; ++r) {
            sHT[wv][quad * 4 + r][nidx]      = (_Float16)c0[r];
            sHT[wv][quad * 4 + r][16 + nidx] = (_Float16)c1[r];
        }
        // B2[k=quad*8+j][n=x'=nidx] = sHT[wv][nidx][k] (contiguous, aligned)
        f16x8 hb = *(const f16x8*)&sHT[wv][nidx][quad * 8];
        accv[mm] = mfma_f16(af, hb, z);
    }

    // Epilogue: lane holds 4 maps x 4 pixels at y = y0+quad*4+r, x = x0+cb+nidx
    const float C1v = 1e-4f, C2v = 9e-4f;  // L = 1 (inputs uniform [0,1))
    const float cm = gw.cm;
    float lsum = 0.f;
    {
        const int xl = cb + nidx;
        const int x = x0 + xl;
        const int lc0 = xl >> 4, lc1 = (xl + 10) >> 4;
        #pragma unroll
        for (int r = 0; r < 4; ++r) {
            int yl = quad * 4 + r;
            int y = y0 + yl;
            if (y < OUTD && x < OUTD) {
                int lr1 = (yl + 10) >> 4;
                int validm = sdil[lc0] & sdil[lc1] &
                             sdil[5 * lr1 + lc0] & sdil[5 * lr1 + lc1];
                float mu1 = accv[0][r] * cm, mu2 = accv[1][r] * cm;
                float Sab = accv[2][r] * cm, Sss = accv[3][r] * cm;
                float mu1s = mu1 * mu1, mu2s = mu2 * mu2, mu12 = mu1 * mu2;
                float sg12 = Sab - mu12;
                float sigS = Sss - mu1s - mu2s;
                float num = (2.f * mu12 + C1v) * (2.f * sg12 + C2v);
                float den = (mu1s + mu2s + C1v) * (sigS + C2v);
                if (validm) lsum += __fdividef(num, den);
            }
        }
    }

    // block reduction -> one float partial per block (deterministic, no atomics)
    #pragma unroll
    for (int off = 32; off >= 1; off >>= 1) lsum += __shfl_xor(lsum, off);
    if ((tid & 63) == 0) wsum[tid >> 6] = lsum;
    __syncthreads();
    if (tid == 0)
        partial[((int)blockIdx.z * GY + (int)blockIdx.y) * GX + (int)blockIdx.x] =
            wsum[0] + wsum[1] + wsum[2] + wsum[3];
}

// Kernel 3: reduce partials, divide by element count
__global__ __launch_bounds__(256) void finalize_kernel(const float* __restrict__ partial,
                                                       float* __restrict__ out) {
    __shared__ double sd[256];
    double s = 0.0;
    const f32x4* p4 = (const f32x4*)partial;
    for (int i = threadIdx.x; i < NPARTIAL / 4; i += 256) {
        f32x4 vv = p4[i];
        s += (double)vv.x + (double)vv.y + (double)vv.z + (double)vv.w;
    }
    sd[threadIdx.x] = s;
    __syncthreads();
    for (int st = 128; st >= 1; st >>= 1) {
        if (threadIdx.x < st) sd[threadIdx.x] += sd[threadIdx.x + st];
        __syncthreads();
    }
    if (threadIdx.x == 0) out[0] = (float)(sd[0] / 12096192.0);  // 16*3*502*502
}

// Round a positive normal double to the nearest fp16-representable float (RTNE).
static inline float fp16_rtne(double x) {
    float f = (float)x;
    uint32_t u; memcpy(&u, &f, 4);
    // drop 13 mantissa bits (23 -> 10), RTNE with carry into exponent
    u = (u + 0xFFFu + ((u >> 13) & 1u)) & ~0x1FFFu;
    memcpy(&f, &u, 4);
    return f;
}

extern "C" void kernel_launch(void* const* d_in, const int* in_sizes, int n_in,
                              void* d_out, int out_size, void* d_ws, size_t ws_size,
                              hipStream_t stream) {
    const float* img1 = (const float*)d_in[0];
    const float* img2 = (const float*)d_in[1];
    const int*   mask = (const int*)d_in[2];
    float* out = (float*)d_out;

    char* ws = (char*)d_ws;
    float* partial  = (float*)ws;                        // 12288 floats
    int*   smallbuf = (int*)(ws + NPARTIAL * 4);         // 16*32*32 ints

    // Gaussian(sigma=1.5), normalized in double, then each tap rounded to
    // fp16 (RTNE). cm = 1/(sum of rounded taps)^2 removes the systematic
    // scale error of fp16 conv weights (applied to all 4 maps in epilogue).
    GW gw;
    double gd[NTAP], gsum = 0.0;
    for (int i = 0; i < NTAP; ++i) {
        double x = (double)(i - 5);
        gd[i] = exp(-(x * x) / 4.5);
        gsum += gd[i];
    }
    double wsumr = 0.0;
    for (int i = 0; i < NTAP; ++i) {
        gw.g[i] = fp16_rtne(gd[i] / gsum);
        wsumr += (double)gw.g[i];
    }
    gw.cm = (float)(1.0 / (wsumr * wsumr));

    patch_max_kernel<<<dim3(32, 16), 256, 0, stream>>>(mask, smallbuf);
    ssim_kernel<<<dim3(GX, GY, 48), 256, 0, stream>>>(img1, img2, smallbuf, partial, gw);
    finalize_kernel<<<1, 256, 0, stream>>>(partial, out);
}